// Round 13
// baseline (665.168 us; speedup 1.0000x reference)
//
#include <hip/hip_runtime.h>
#include <hip/hip_fp16.h>
#include <stdint.h>

#define N_NODES 50000
#define N_EDGES 800000
#define DIM_IN  16
#define H       512
#define GRAPHS  256
#define AK      1024          // A row: [h bf16 (512) | agg f16 (512)]
#define KT_STEPS 32           // B pack: kt 0-15 W_root bf16, 16-31 W_neigh f16

typedef __attribute__((ext_vector_type(8))) short short8;
typedef __attribute__((ext_vector_type(8))) _Float16 half8;
typedef __attribute__((ext_vector_type(4))) float f32x4;
typedef __attribute__((ext_vector_type(2))) float f32x2;
typedef __attribute__((ext_vector_type(4))) unsigned int u32x4;
typedef __attribute__((ext_vector_type(2))) unsigned int u32x2;

__device__ __forceinline__ unsigned short f2bf(float f) {
    unsigned int u = __float_as_uint(f);
    return (unsigned short)((u + 0x7fffu + ((u >> 16) & 1u)) >> 16);
}
__device__ __forceinline__ unsigned short f2h(float f) {
    __half h = __float2half(f);
    return *(unsigned short*)&h;
}

#define GLOAD_LDS16(g, l) __builtin_amdgcn_global_load_lds( \
    (const __attribute__((address_space(1))) void*)(g), \
    (__attribute__((address_space(3))) void*)(l), 16, 0, 0)

// ---------------- CSR build ----------------
__global__ void k_count(const int* __restrict__ ei, int* __restrict__ deg) {
    int t = blockIdx.x * 256 + threadIdx.x;
    if (t < N_EDGES) atomicAdd(&deg[ei[N_EDGES + t]], 1);
}

__global__ void k_scan1(const int* __restrict__ deg, int* __restrict__ off, int* __restrict__ bsum) {
    __shared__ int ls[512];
    int t = threadIdx.x; int gi = blockIdx.x * 512 + t;
    ls[t] = (gi < N_NODES) ? deg[gi] : 0;
    __syncthreads();
    for (int o = 1; o < 512; o <<= 1) {
        int u = (t >= o) ? ls[t - o] : 0;
        __syncthreads();
        ls[t] += u;
        __syncthreads();
    }
    if (gi < N_NODES) off[gi] = (t == 0) ? 0 : ls[t - 1];
    if (t == 511) bsum[blockIdx.x] = ls[511];
}

__global__ void k_scan2(int* bsum) {
    __shared__ int ls[128];
    int t = threadIdx.x;
    ls[t] = (t < 98) ? bsum[t] : 0;
    __syncthreads();
    for (int o = 1; o < 128; o <<= 1) {
        int u = (t >= o) ? ls[t - o] : 0;
        __syncthreads();
        ls[t] += u;
        __syncthreads();
    }
    if (t < 98) bsum[t] = (t == 0) ? 0 : ls[t - 1];
}

__global__ void k_scan3(int* __restrict__ off, const int* __restrict__ bsum, int* __restrict__ cur) {
    int i = blockIdx.x * 256 + threadIdx.x;
    if (i < N_NODES) {
        int v = off[i] + bsum[i >> 9];
        off[i] = v; cur[i] = v;
    }
    if (i == 0) off[N_NODES] = N_EDGES;
}

__global__ void k_fill(const int* __restrict__ ei, int* __restrict__ cur, int* __restrict__ csr) {
    int t = blockIdx.x * 256 + threadIdx.x;
    if (t < N_EDGES) {
        int d = ei[N_EDGES + t];
        int p = atomicAdd(&cur[d], 1);
        csr[p] = ei[t];
    }
}

// ---------------- input projection: h0 = x @ W_in + b_in (fp32 -> bf16 + fp8 mirror) --------
__global__ void k_gemm_in(const float* __restrict__ x, const float* __restrict__ Win,
                          const float* __restrict__ bin, unsigned short* A,
                          unsigned char* __restrict__ h8) {
    __shared__ float Wl[DIM_IN * H];
    __shared__ float xl[16 * DIM_IN];
    __shared__ float bl[H];
    int t = threadIdx.x;
    const float4* W4 = (const float4*)Win;
    float4* Wl4 = (float4*)Wl;
#pragma unroll
    for (int i = 0; i < 8; i++) Wl4[t + 256 * i] = W4[t + 256 * i];
    bl[t] = bin[t]; bl[t + 256] = bin[t + 256];
    int r0 = blockIdx.x * 16;
    {
        int r = t >> 4, k = t & 15;
        int row = r0 + r;
        xl[t] = (row < N_NODES) ? x[row * DIM_IN + k] : 0.f;
    }
    __syncthreads();
    int c0 = t * 2;
    for (int r = 0; r < 16; r++) {
        int row = r0 + r;
        if (row >= N_NODES) break;
        float a0 = bl[c0], a1 = bl[c0 + 1];
#pragma unroll
        for (int k = 0; k < 16; k++) {
            float xv = xl[r * 16 + k];
            a0 += xv * Wl[k * 512 + c0];
            a1 += xv * Wl[k * 512 + c0 + 1];
        }
        unsigned int pack = ((unsigned int)f2bf(a1) << 16) | (unsigned int)f2bf(a0);
        *(unsigned int*)&A[(size_t)row * AK + c0] = pack;
        unsigned int pk8 = (unsigned int)__builtin_amdgcn_cvt_pk_fp8_f32(a0, a1, 0, false);
        *(unsigned short*)&h8[(size_t)row * 512 + c0] = (unsigned short)(pk8 & 0xffffu);
    }
}

// ---------------- fp8 mirror refresh: h8 = e4m3(h) (after layers 0,1) ----------------
__global__ void k_tofp8(const unsigned short* __restrict__ A, unsigned char* __restrict__ h8) {
    int i = blockIdx.x * 256 + threadIdx.x;          // one group of 8 elems
    if (i >= N_NODES * 64) return;
    int row = i >> 6, g = i & 63;
    u32x4 v = *(const u32x4*)&A[(size_t)row * AK + g * 8];
    float f[8];
#pragma unroll
    for (int j = 0; j < 4; j++) {
        f[2 * j]     = __uint_as_float(v[j] << 16);
        f[2 * j + 1] = __uint_as_float(v[j] & 0xffff0000u);
    }
    int w0 = __builtin_amdgcn_cvt_pk_fp8_f32(f[0], f[1], 0, false);
    w0 = __builtin_amdgcn_cvt_pk_fp8_f32(f[2], f[3], w0, true);
    int w1 = __builtin_amdgcn_cvt_pk_fp8_f32(f[4], f[5], 0, false);
    w1 = __builtin_amdgcn_cvt_pk_fp8_f32(f[6], f[7], w1, true);
    u32x2 o; o[0] = (unsigned int)w0; o[1] = (unsigned int)w1;
    *(u32x2*)&h8[(size_t)row * 512 + g * 8] = o;
}

// ---------------- neighbor aggregation from fp8 mirror: agg = sum_{e} h8[src] -> f16 --------
__global__ void k_aggregate(const int* __restrict__ off, const int* __restrict__ csr,
                            const unsigned char* __restrict__ h8, unsigned short* A) {
    int w = threadIdx.x >> 6, lane = threadIdx.x & 63;
    int n = blockIdx.x * 4 + w;
    if (n >= N_NODES) return;
    int s = off[n], e = off[n + 1];
    float acc[8] = {0, 0, 0, 0, 0, 0, 0, 0};
    const unsigned char* Ab = h8 + (size_t)lane * 8;

#define ACC_FP8(vv) { \
    f32x2 p0 = __builtin_amdgcn_cvt_pk_f32_fp8((int)(vv)[0], false); \
    f32x2 p1 = __builtin_amdgcn_cvt_pk_f32_fp8((int)(vv)[0], true);  \
    f32x2 p2 = __builtin_amdgcn_cvt_pk_f32_fp8((int)(vv)[1], false); \
    f32x2 p3 = __builtin_amdgcn_cvt_pk_f32_fp8((int)(vv)[1], true);  \
    acc[0] += p0[0]; acc[1] += p0[1]; acc[2] += p1[0]; acc[3] += p1[1]; \
    acc[4] += p2[0]; acc[5] += p2[1]; acc[6] += p3[0]; acc[7] += p3[1]; }

    for (int base = s; base < e; base += 64) {
        int m = e - base; if (m > 64) m = 64;
        int idx = (lane < m) ? csr[base + lane] : 0;
        int g = 0;
        for (; g + 4 <= m; g += 4) {
            int sn0 = __shfl(idx, g);
            int sn1 = __shfl(idx, g + 1);
            int sn2 = __shfl(idx, g + 2);
            int sn3 = __shfl(idx, g + 3);
            u32x2 v0 = *(const u32x2*)(Ab + ((size_t)sn0 << 9));
            u32x2 v1 = *(const u32x2*)(Ab + ((size_t)sn1 << 9));
            u32x2 v2 = *(const u32x2*)(Ab + ((size_t)sn2 << 9));
            u32x2 v3 = *(const u32x2*)(Ab + ((size_t)sn3 << 9));
            ACC_FP8(v0); ACC_FP8(v1); ACC_FP8(v2); ACC_FP8(v3);
        }
        for (; g < m; g++) {
            int sn = __shfl(idx, g);
            u32x2 v = *(const u32x2*)(Ab + ((size_t)sn << 9));
            ACC_FP8(v);
        }
    }
#undef ACC_FP8
    u32x4 hv;
#pragma unroll
    for (int j = 0; j < 4; j++) {
        hv[j] = ((unsigned int)f2h(acc[2 * j + 1]) << 16) | (unsigned int)f2h(acc[2 * j]);
    }
    *(u32x4*)&A[(size_t)n * AK + 512 + lane * 8] = hv;
}

// ---------------- fused conv GEMM + bias + LayerNorm + ReLU ----------------
// EXACT R6 structure (proven 94 us): 64 rows x 512 cols, 512 threads = 8 waves,
// wave (wr,wc) = 16 rows x 256 cols (16 frags), K=1024 in 32 steps of 32,
// 2-phase dbuf, STAGE(kt+1) before compute, ONE __syncthreads per kt.
__global__ __launch_bounds__(512, 4)
void k_gemm_layer(unsigned short* A, const unsigned short* __restrict__ Bp,
                  const float* __restrict__ bias, const float* __restrict__ gamma,
                  const float* __restrict__ beta) {
    extern __shared__ __align__(16) char smem[];   // 2 x (B 32KB + A 4KB) = 72KB
    int t = threadIdx.x, w = t >> 6, lane = t & 63;
    int wr = w >> 1, wc = w & 1;
    int rblk = blockIdx.x * 64;

    f32x4 acc[16];
#pragma unroll
    for (int i = 0; i < 16; i++) acc[i] = (f32x4)(0.f);

    int rowSt = rblk + w * 16 + (lane & 15);           // waves 0-3 stage A row-group w
    if (rowSt >= N_NODES) rowSt = N_NODES - 1;
    const unsigned short* gAst = A + (size_t)rowSt * AK + (lane >> 4) * 8;
    const unsigned short* gB = Bp + (size_t)lane * 8;

    auto STAGE = [&](int kt, int buf) {
        char* base = smem + buf * 36864;
        const unsigned short* gBk = gB + (size_t)kt * 32 * 512;
#pragma unroll
        for (int i = 0; i < 4; i++) {
            int cf = w * 4 + i;
            GLOAD_LDS16(gBk + (size_t)cf * 512, base + cf * 1024);
        }
        if (w < 4) GLOAD_LDS16(gAst + kt * 32, base + 32768 + w * 1024);
    };

    STAGE(0, 0);
    __syncthreads();

    for (int kt = 0; kt < 16; kt++) {
        int cur = kt & 1;
        STAGE(kt + 1, cur ^ 1);
        char* base = smem + cur * 36864;
        short8 av = *(const short8*)(base + 32768 + wr * 1024 + lane * 16);
#pragma unroll
        for (int i = 0; i < 16; i++) {
            short8 bv = *(const short8*)(base + (wc * 16 + i) * 1024 + lane * 16);
            acc[i] = __builtin_amdgcn_mfma_f32_16x16x32_bf16(av, bv, acc[i], 0, 0, 0);
        }
        __syncthreads();
    }
    for (int kt = 16; kt < 32; kt++) {
        int cur = kt & 1;
        if (kt + 1 < 32) STAGE(kt + 1, cur ^ 1);
        char* base = smem + cur * 36864;
        half8 av = *(const half8*)(base + 32768 + wr * 1024 + lane * 16);
#pragma unroll
        for (int i = 0; i < 16; i++) {
            half8 bv = *(const half8*)(base + (wc * 16 + i) * 1024 + lane * 16);
            acc[i] = __builtin_amdgcn_mfma_f32_16x16x32_f16(av, bv, acc[i], 0, 0, 0);
        }
        __syncthreads();
    }

    // ---- epilogue: bias + LN (cross-wave over 2 col-halves) + ReLU + bf16 store ----
    int g = lane >> 4, cl = lane & 15;
    float s[4] = {0, 0, 0, 0}, q[4] = {0, 0, 0, 0};
#pragma unroll
    for (int i = 0; i < 16; i++) {
        int col = wc * 256 + i * 16 + cl;
        float b = bias[col];
        f32x4 a = acc[i];
#pragma unroll
        for (int r = 0; r < 4; r++) {
            float v = a[r] + b;
            a[r] = v;
            s[r] += v;
            q[r] += v * v;
        }
        acc[i] = a;
    }
#pragma unroll
    for (int m = 1; m < 16; m <<= 1) {
#pragma unroll
        for (int r = 0; r < 4; r++) {
            s[r] += __shfl_xor(s[r], m);
            q[r] += __shfl_xor(q[r], m);
        }
    }
    float* pbuf = (float*)smem;          // [4rg][2wc][4g][4r] x {s,q}
    if (cl == 0) {
#pragma unroll
        for (int r = 0; r < 4; r++) {
            pbuf[((wr * 2 + wc) * 16) + g * 4 + r] = s[r];
            pbuf[256 + ((wr * 2 + wc) * 16) + g * 4 + r] = q[r];
        }
    }
    __syncthreads();
    float mean[4], rs[4];
#pragma unroll
    for (int r = 0; r < 4; r++) {
        float sf = pbuf[(wr * 2) * 16 + g * 4 + r] + pbuf[(wr * 2 + 1) * 16 + g * 4 + r];
        float qf = pbuf[256 + (wr * 2) * 16 + g * 4 + r] + pbuf[256 + (wr * 2 + 1) * 16 + g * 4 + r];
        mean[r] = sf * (1.f / 512.f);
        float var = qf * (1.f / 512.f) - mean[r] * mean[r];
        rs[r] = rsqrtf(var + 1e-5f);
    }
    int row0 = rblk + wr * 16 + g * 4;
    bool ok[4];
#pragma unroll
    for (int r = 0; r < 4; r++) ok[r] = (row0 + r) < N_NODES;
#pragma unroll
    for (int i = 0; i < 16; i++) {
        int col = wc * 256 + i * 16 + cl;
        float ga = gamma[col], be = beta[col];
        f32x4 a = acc[i];
#pragma unroll
        for (int r = 0; r < 4; r++) {
            float o = (a[r] - mean[r]) * rs[r] * ga + be;
            o = fmaxf(o, 0.f);
            if (ok[r]) A[(size_t)(row0 + r) * AK + col] = f2bf(o);
        }
    }
}

// ---------------- mean pool per graph (batch sorted) ----------------
__global__ void k_pool(const unsigned short* __restrict__ A, const int* __restrict__ batch,
                       float* __restrict__ pooled) {
    __shared__ float part[4 * 512];
    __shared__ int se[2];
    int g = blockIdx.x, t = threadIdx.x, w = t >> 6, lane = t & 63;
    if (t == 0) {
        int lo = 0, hi = N_NODES;
        while (lo < hi) { int m = (lo + hi) >> 1; if (batch[m] < g) lo = m + 1; else hi = m; }
        se[0] = lo;
        int lo2 = lo; hi = N_NODES;
        while (lo2 < hi) { int m = (lo2 + hi) >> 1; if (batch[m] < g + 1) lo2 = m + 1; else hi = m; }
        se[1] = lo2;
    }
    __syncthreads();
    int s = se[0], e = se[1];
    float acc[8] = {0, 0, 0, 0, 0, 0, 0, 0};
    for (int row = s + w; row < e; row += 4) {
        u32x4 v = *(const u32x4*)&A[(size_t)row * AK + lane * 8];
#pragma unroll
        for (int j = 0; j < 4; j++) {
            unsigned int uu = v[j];
            acc[2 * j]     += __uint_as_float(uu << 16);
            acc[2 * j + 1] += __uint_as_float(uu & 0xffff0000u);
        }
    }
#pragma unroll
    for (int j = 0; j < 8; j++) part[w * 512 + j * 64 + lane] = acc[j];
    __syncthreads();
    float cnt = fmaxf((float)(e - s), 1.f);
    for (int sidx = t; sidx < 512; sidx += 256) {
        float v = part[sidx] + part[512 + sidx] + part[1024 + sidx] + part[1536 + sidx];
        int col = (sidx & 63) * 8 + (sidx >> 6);
        pooled[(size_t)g * 512 + col] = v / cnt;
    }
}

// ---------------- final: out = pooled @ W_out + b_out (fp32) ----------------
// 32 blocks x 8 graphs: W_out streamed ONCE per block (32 MB total vs 256 MB
// at 1 block/graph).  pooled rows staged in LDS; 16 FMA per 8B of W_out.
__global__ __launch_bounds__(256)
void k_out(const float* __restrict__ pooled, const float* __restrict__ Wout,
           const float* __restrict__ bout, float* __restrict__ out) {
    __shared__ float pl[8 * 512];
    int t = threadIdx.x;
    int g0 = blockIdx.x * 8;
#pragma unroll
    for (int i = 0; i < 16; i++) {
        int idx = i * 256 + t;
        pl[idx] = pooled[(size_t)g0 * 512 + idx];
    }
    __syncthreads();
    int c0 = t * 2;
    float a[8][2];
#pragma unroll
    for (int g = 0; g < 8; g++) { a[g][0] = bout[c0]; a[g][1] = bout[c0 + 1]; }
    for (int k = 0; k < 512; k++) {
        float2 wv = *(const float2*)&Wout[(size_t)k * 512 + c0];
#pragma unroll
        for (int g = 0; g < 8; g++) {
            float p = pl[g * 512 + k];
            a[g][0] += p * wv.x;
            a[g][1] += p * wv.y;
        }
    }
#pragma unroll
    for (int g = 0; g < 8; g++) {
        out[(size_t)(g0 + g) * 512 + c0]     = a[g][0];
        out[(size_t)(g0 + g) * 512 + c0 + 1] = a[g][1];
    }
}

// ---------------- pack B = [W_root bf16 ; W_neigh f16] into MFMA fragment order ----------------
__global__ void k_pack_b(const float* __restrict__ Wr, const float* __restrict__ Wn,
                         unsigned short* __restrict__ Bp) {
    int t = blockIdx.x * 256 + threadIdx.x;
    if (t >= 3 * KT_STEPS * 32 * 64) return;
    int lane = t & 63;
    int u = t >> 6;
    int cf = u & 31; u >>= 5;
    int kt = u % KT_STEPS;
    int l  = u / KT_STEPS;
    int col = cf * 16 + (lane & 15);
    int kr0 = (kt & 15) * 32 + (lane >> 4) * 8;
    bool isRoot = (kt < 16);
    const float* W = (isRoot ? Wr : Wn) + (size_t)l * H * H;
    unsigned int words[4];
#pragma unroll
    for (int p = 0; p < 4; p++) {
        float v0 = W[(size_t)(kr0 + 2 * p) * H + col];
        float v1 = W[(size_t)(kr0 + 2 * p + 1) * H + col];
        unsigned short b0 = isRoot ? f2bf(v0) : f2h(v0);
        unsigned short b1 = isRoot ? f2bf(v1) : f2h(v1);
        words[p] = ((unsigned int)b1 << 16) | (unsigned int)b0;
    }
    u32x4 v; v[0] = words[0]; v[1] = words[1]; v[2] = words[2]; v[3] = words[3];
    *(u32x4*)&Bp[(size_t)t * 8] = v;
}

extern "C" void kernel_launch(void* const* d_in, const int* in_sizes, int n_in,
                              void* d_out, int out_size, void* d_ws, size_t ws_size,
                              hipStream_t stream) {
    const float* x     = (const float*)d_in[0];
    const int*   ei    = (const int*)d_in[1];
    const int*   batch = (const int*)d_in[2];
    const float* Win   = (const float*)d_in[3];
    const float* bin   = (const float*)d_in[4];
    const float* Wr    = (const float*)d_in[5];
    const float* Wn    = (const float*)d_in[6];
    const float* bconv = (const float*)d_in[7];
    const float* gamma = (const float*)d_in[8];
    const float* beta  = (const float*)d_in[9];
    const float* Wout  = (const float*)d_in[10];
    const float* bout  = (const float*)d_in[11];
    float* out = (float*)d_out;

    char* p = (char*)d_ws;
    auto carve = [&](size_t bytes) { char* r = p; p += (bytes + 255) & ~(size_t)255; return r; };
    unsigned short* A  = (unsigned short*)carve((size_t)N_NODES * AK * 2);
    unsigned char*  h8 = (unsigned char*)carve((size_t)N_NODES * 512);
    unsigned short* Bp = (unsigned short*)carve((size_t)3 * KT_STEPS * 32 * 64 * 8 * 2);
    int* csr  = (int*)carve((size_t)N_EDGES * 4);
    int* deg  = (int*)carve((size_t)N_NODES * 4);
    int* off  = (int*)carve((size_t)(N_NODES + 1) * 4);
    int* cur  = (int*)carve((size_t)N_NODES * 4);
    int* bsum = (int*)carve(1024);
    float* pooled = (float*)carve((size_t)GRAPHS * H * 4);

    hipMemsetAsync(deg, 0, (size_t)N_NODES * 4, stream);
    k_count<<<(N_EDGES + 255) / 256, 256, 0, stream>>>(ei, deg);
    k_scan1<<<98, 512, 0, stream>>>(deg, off, bsum);
    k_scan2<<<1, 128, 0, stream>>>(bsum);
    k_scan3<<<(N_NODES + 255) / 256, 256, 0, stream>>>(off, bsum, cur);
    k_fill<<<(N_EDGES + 255) / 256, 256, 0, stream>>>(ei, cur, csr);
    k_gemm_in<<<(N_NODES + 15) / 16, 256, 0, stream>>>(x, Win, bin, A, h8);
    k_pack_b<<<(3 * KT_STEPS * 32 * 64) / 256, 256, 0, stream>>>(Wr, Wn, Bp);
    for (int l = 0; l < 3; l++) {
        k_aggregate<<<(N_NODES + 3) / 4, 256, 0, stream>>>(off, csr, h8, A);
        k_gemm_layer<<<(N_NODES + 63) / 64, 512, 73728, stream>>>(
            A, Bp + (size_t)l * KT_STEPS * 32 * 64 * 8,
            bconv + (size_t)l * H, gamma + (size_t)l * H, beta + (size_t)l * H);
        if (l < 2)
            k_tofp8<<<(N_NODES * 64 + 255) / 256, 256, 0, stream>>>(A, h8);
    }
    k_pool<<<GRAPHS, 256, 0, stream>>>(A, batch, pooled);
    k_out<<<32, 256, 0, stream>>>(pooled, Wout, bout, out);
}

// Round 15
// 623.115 us; speedup vs baseline: 1.0675x; 1.0675x over previous
//
#include <hip/hip_runtime.h>
#include <hip/hip_fp16.h>
#include <stdint.h>

#define N_NODES 50000
#define N_EDGES 800000
#define DIM_IN  16
#define H       512
#define GRAPHS  256

typedef __attribute__((ext_vector_type(8))) short short8;
typedef __attribute__((ext_vector_type(8))) _Float16 half8;
typedef __attribute__((ext_vector_type(4))) float f32x4;
typedef __attribute__((ext_vector_type(2))) float f32x2;
typedef __attribute__((ext_vector_type(4))) unsigned int u32x4;
typedef __attribute__((ext_vector_type(2))) unsigned int u32x2;

__device__ __forceinline__ unsigned short f2bf(float f) {
    unsigned int u = __float_as_uint(f);
    return (unsigned short)((u + 0x7fffu + ((u >> 16) & 1u)) >> 16);
}
__device__ __forceinline__ unsigned short f2h(float f) {
    __half h = __float2half(f);
    return *(unsigned short*)&h;
}

#define GLOAD_LDS16(g, l) __builtin_amdgcn_global_load_lds( \
    (const __attribute__((address_space(1))) void*)(g), \
    (__attribute__((address_space(3))) void*)(l), 16, 0, 0)

// ---------------- CSR build ----------------
__global__ void k_count(const int* __restrict__ ei, int* __restrict__ deg) {
    int t = blockIdx.x * 256 + threadIdx.x;
    if (t < N_EDGES) atomicAdd(&deg[ei[N_EDGES + t]], 1);
}

__global__ void k_scan1(const int* __restrict__ deg, int* __restrict__ off, int* __restrict__ bsum) {
    __shared__ int ls[512];
    int t = threadIdx.x; int gi = blockIdx.x * 512 + t;
    ls[t] = (gi < N_NODES) ? deg[gi] : 0;
    __syncthreads();
    for (int o = 1; o < 512; o <<= 1) {
        int u = (t >= o) ? ls[t - o] : 0;
        __syncthreads();
        ls[t] += u;
        __syncthreads();
    }
    if (gi < N_NODES) off[gi] = (t == 0) ? 0 : ls[t - 1];
    if (t == 511) bsum[blockIdx.x] = ls[511];
}

__global__ void k_scan2(int* bsum) {
    __shared__ int ls[128];
    int t = threadIdx.x;
    ls[t] = (t < 98) ? bsum[t] : 0;
    __syncthreads();
    for (int o = 1; o < 128; o <<= 1) {
        int u = (t >= o) ? ls[t - o] : 0;
        __syncthreads();
        ls[t] += u;
        __syncthreads();
    }
    if (t < 98) bsum[t] = (t == 0) ? 0 : ls[t - 1];
}

__global__ void k_scan3(int* __restrict__ off, const int* __restrict__ bsum, int* __restrict__ cur) {
    int i = blockIdx.x * 256 + threadIdx.x;
    if (i < N_NODES) {
        int v = off[i] + bsum[i >> 9];
        off[i] = v; cur[i] = v;
    }
    if (i == 0) off[N_NODES] = N_EDGES;
}

__global__ void k_fill(const int* __restrict__ ei, int* __restrict__ cur, int* __restrict__ csr) {
    int t = blockIdx.x * 256 + threadIdx.x;
    if (t < N_EDGES) {
        int d = ei[N_EDGES + t];
        int p = atomicAdd(&cur[d], 1);
        csr[p] = ei[t];
    }
}

// ---------------- input projection: h0 = x @ W_in + b_in -> fp8 mirror only ----------------
__global__ void k_gemm_in(const float* __restrict__ x, const float* __restrict__ Win,
                          const float* __restrict__ bin, unsigned char* __restrict__ h8) {
    __shared__ float Wl[DIM_IN * H];
    __shared__ float xl[16 * DIM_IN];
    __shared__ float bl[H];
    int t = threadIdx.x;
    const float4* W4 = (const float4*)Win;
    float4* Wl4 = (float4*)Wl;
#pragma unroll
    for (int i = 0; i < 8; i++) Wl4[t + 256 * i] = W4[t + 256 * i];
    bl[t] = bin[t]; bl[t + 256] = bin[t + 256];
    int r0 = blockIdx.x * 16;
    {
        int r = t >> 4, k = t & 15;
        int row = r0 + r;
        xl[t] = (row < N_NODES) ? x[row * DIM_IN + k] : 0.f;
    }
    __syncthreads();
    int c0 = t * 2;
    for (int r = 0; r < 16; r++) {
        int row = r0 + r;
        if (row >= N_NODES) break;
        float a0 = bl[c0], a1 = bl[c0 + 1];
#pragma unroll
        for (int k = 0; k < 16; k++) {
            float xv = xl[r * 16 + k];
            a0 += xv * Wl[k * 512 + c0];
            a1 += xv * Wl[k * 512 + c0 + 1];
        }
        unsigned int pk8 = (unsigned int)__builtin_amdgcn_cvt_pk_fp8_f32(a0, a1, 0, false);
        *(unsigned short*)&h8[(size_t)row * 512 + c0] = (unsigned short)(pk8 & 0xffffu);
    }
}

// ---------------- neighbor aggregation: agg[n] = sum_src h8[src] -> f16 [N][512] ----------
__global__ void k_aggregate(const int* __restrict__ off, const int* __restrict__ csr,
                            const unsigned char* __restrict__ h8, unsigned short* __restrict__ agg) {
    int w = threadIdx.x >> 6, lane = threadIdx.x & 63;
    int n = blockIdx.x * 4 + w;
    if (n >= N_NODES) return;
    int s = off[n], e = off[n + 1];
    float acc[8] = {0, 0, 0, 0, 0, 0, 0, 0};
    const unsigned char* Ab = h8 + (size_t)lane * 8;

#define ACC_FP8(vv) { \
    f32x2 p0 = __builtin_amdgcn_cvt_pk_f32_fp8((int)(vv)[0], false); \
    f32x2 p1 = __builtin_amdgcn_cvt_pk_f32_fp8((int)(vv)[0], true);  \
    f32x2 p2 = __builtin_amdgcn_cvt_pk_f32_fp8((int)(vv)[1], false); \
    f32x2 p3 = __builtin_amdgcn_cvt_pk_f32_fp8((int)(vv)[1], true);  \
    acc[0] += p0[0]; acc[1] += p0[1]; acc[2] += p1[0]; acc[3] += p1[1]; \
    acc[4] += p2[0]; acc[5] += p2[1]; acc[6] += p3[0]; acc[7] += p3[1]; }

    for (int base = s; base < e; base += 64) {
        int m = e - base; if (m > 64) m = 64;
        int idx = (lane < m) ? csr[base + lane] : 0;
        int g = 0;
        for (; g + 4 <= m; g += 4) {
            int sn0 = __shfl(idx, g);
            int sn1 = __shfl(idx, g + 1);
            int sn2 = __shfl(idx, g + 2);
            int sn3 = __shfl(idx, g + 3);
            u32x2 v0 = *(const u32x2*)(Ab + ((size_t)sn0 << 9));
            u32x2 v1 = *(const u32x2*)(Ab + ((size_t)sn1 << 9));
            u32x2 v2 = *(const u32x2*)(Ab + ((size_t)sn2 << 9));
            u32x2 v3 = *(const u32x2*)(Ab + ((size_t)sn3 << 9));
            ACC_FP8(v0); ACC_FP8(v1); ACC_FP8(v2); ACC_FP8(v3);
        }
        for (; g < m; g++) {
            int sn = __shfl(idx, g);
            u32x2 v = *(const u32x2*)(Ab + ((size_t)sn << 9));
            ACC_FP8(v);
        }
    }
#undef ACC_FP8
    u32x4 hv;
#pragma unroll
    for (int j = 0; j < 4; j++) {
        hv[j] = ((unsigned int)f2h(acc[2 * j + 1]) << 16) | (unsigned int)f2h(acc[2 * j]);
    }
    *(u32x4*)&agg[(size_t)n * 512 + lane * 8] = hv;
}

// ---------------- fused conv GEMM + bias + LN + ReLU (fp8 root half + f16 agg half) --------
// 64 rows x 512 cols, 512 thr = 8 waves (4 rg x 2 ch); wave = 16 rows x 256 cols (16 frags).
// kt 0-15: h8 fp8 @ W_root fp8 (mfma fp8_fp8, B-stage 16KB); kt 16-31: agg f16 @ W_neigh f16
// (B-stage 32KB).  A operands: per-lane DIRECT global->register (no LDS), prefetched 1 kt
// into the NEXT register (a8n/a16n); rotation at iteration end.  R6-proven sync structure.
__global__ __launch_bounds__(512, 4)
void k_gemm_layer(const unsigned char* __restrict__ h8in, const unsigned short* __restrict__ agg,
                  unsigned char* __restrict__ h8out, unsigned short* __restrict__ hout,
                  const unsigned char* __restrict__ Bp8, const unsigned short* __restrict__ Bpf,
                  const float* __restrict__ bias, const float* __restrict__ gamma,
                  const float* __restrict__ beta, int lastLayer) {
    extern __shared__ __align__(16) char smem[];   // 2 x 32KB B slots
    int t = threadIdx.x, w = t >> 6, lane = t & 63;
    int wr = w >> 1, wc = w & 1;
    int rblk = blockIdx.x * 64;

    f32x4 acc[16];
#pragma unroll
    for (int i = 0; i < 16; i++) acc[i] = (f32x4)(0.f);

    int rowA = rblk + wr * 16 + (lane & 15);
    if (rowA >= N_NODES) rowA = N_NODES - 1;
    const unsigned char* aRow8 = h8in + (size_t)rowA * 512 + (lane >> 4) * 8;
    const unsigned char* aRowF = (const unsigned char*)agg + (size_t)rowA * 1024 + (lane >> 4) * 16;
    const unsigned char* BpfB = (const unsigned char*)Bpf;

    auto STAGE8 = [&](int kt, int buf) {
        const unsigned char* g = Bp8 + (size_t)kt * 16384 + w * 2048 + lane * 16;
        char* base = smem + buf * 32768 + w * 2048;
        GLOAD_LDS16(g, base);
        GLOAD_LDS16(g + 1024, base + 1024);
    };
    auto STAGEF = [&](int ktf, int buf) {
        const unsigned char* g = BpfB + (size_t)ktf * 32768 + lane * 16;
        char* base = smem + buf * 32768;
#pragma unroll
        for (int i = 0; i < 4; i++) {
            int cf = w * 4 + i;
            GLOAD_LDS16(g + cf * 1024, base + cf * 1024);
        }
    };

    long a8c = *(const long*)(aRow8);
    long a8n = 0;
    half8 a16c = (half8)(_Float16)0, a16n = (half8)(_Float16)0;
    STAGE8(0, 0);
    __syncthreads();

    for (int kt = 0; kt < 32; kt++) {
        int cur = kt & 1;
        // A prefetch for kt+1, always into the NEXT register (rotated at loop end)
        if (kt < 15)       a8n  = *(const long*)(aRow8 + (kt + 1) * 32);
        else if (kt < 31)  a16n = *(const half8*)(aRowF + (kt - 15) * 64);
        // B stage next tile
        if (kt < 15)       STAGE8(kt + 1, cur ^ 1);
        else if (kt < 31)  STAGEF(kt - 15, cur ^ 1);
        char* base = smem + cur * 32768;
        if (kt < 16) {
#pragma unroll
            for (int i = 0; i < 16; i++) {
                long bv = *(const long*)(base + (wc * 16 + i) * 512 + lane * 8);
                acc[i] = __builtin_amdgcn_mfma_f32_16x16x32_fp8_fp8(a8c, bv, acc[i], 0, 0, 0);
            }
        } else {
#pragma unroll
            for (int i = 0; i < 16; i++) {
                half8 bv = *(const half8*)(base + (wc * 16 + i) * 1024 + lane * 16);
                acc[i] = __builtin_amdgcn_mfma_f32_16x16x32_f16(a16c, bv, acc[i], 0, 0, 0);
            }
        }
        __syncthreads();
        a8c = a8n;
        a16c = a16n;
    }

    // ---- epilogue: bias + LN (cross-wave over 2 col-halves) + ReLU ----
    int g = lane >> 4, cl = lane & 15;
    float s[4] = {0, 0, 0, 0}, q[4] = {0, 0, 0, 0};
#pragma unroll
    for (int i = 0; i < 16; i++) {
        int col = wc * 256 + i * 16 + cl;
        float b = bias[col];
        f32x4 a = acc[i];
#pragma unroll
        for (int r = 0; r < 4; r++) {
            float v = a[r] + b;
            a[r] = v;
            s[r] += v;
            q[r] += v * v;
        }
        acc[i] = a;
    }
#pragma unroll
    for (int m = 1; m < 16; m <<= 1) {
#pragma unroll
        for (int r = 0; r < 4; r++) {
            s[r] += __shfl_xor(s[r], m);
            q[r] += __shfl_xor(q[r], m);
        }
    }
    float* pbuf = (float*)smem;
    if (cl == 0) {
#pragma unroll
        for (int r = 0; r < 4; r++) {
            pbuf[((wr * 2 + wc) * 16) + g * 4 + r] = s[r];
            pbuf[256 + ((wr * 2 + wc) * 16) + g * 4 + r] = q[r];
        }
    }
    __syncthreads();
    float mean[4], rs[4];
#pragma unroll
    for (int r = 0; r < 4; r++) {
        float sf = pbuf[(wr * 2) * 16 + g * 4 + r] + pbuf[(wr * 2 + 1) * 16 + g * 4 + r];
        float qf = pbuf[256 + (wr * 2) * 16 + g * 4 + r] + pbuf[256 + (wr * 2 + 1) * 16 + g * 4 + r];
        mean[r] = sf * (1.f / 512.f);
        float var = qf * (1.f / 512.f) - mean[r] * mean[r];
        rs[r] = rsqrtf(var + 1e-5f);
    }
    __syncthreads();   // pbuf reads done before smem reuse below
    int row0 = rblk + wr * 16 + g * 4;
    if (lastLayer) {
        bool ok[4];
#pragma unroll
        for (int r = 0; r < 4; r++) ok[r] = (row0 + r) < N_NODES;
#pragma unroll
        for (int i = 0; i < 16; i++) {
            int col = wc * 256 + i * 16 + cl;
            float ga = gamma[col], be = beta[col];
            f32x4 a = acc[i];
#pragma unroll
            for (int r = 0; r < 4; r++) {
                float o = (a[r] - mean[r]) * rs[r] * ga + be;
                o = fmaxf(o, 0.f);
                if (ok[r]) hout[(size_t)(row0 + r) * 512 + col] = f2bf(o);
            }
        }
    } else {
        // stage fp8 tile in LDS (64 rows x 512 B), then coalesced copy-out
#pragma unroll
        for (int i = 0; i < 16; i++) {
            int col = wc * 256 + i * 16 + cl;
            float ga = gamma[col], be = beta[col];
            f32x4 a = acc[i];
#pragma unroll
            for (int r = 0; r < 4; r++) {
                float o = (a[r] - mean[r]) * rs[r] * ga + be;
                o = fmaxf(o, 0.f);
                unsigned int pk8 = (unsigned int)__builtin_amdgcn_cvt_pk_fp8_f32(o, o, 0, false);
                smem[(wr * 16 + g * 4 + r) * 512 + col] = (char)(pk8 & 0xffu);
            }
        }
        __syncthreads();
        int row = t >> 3, off = (t & 7) * 64;
        if (rblk + row < N_NODES) {
            unsigned char* dst = h8out + (size_t)(rblk + row) * 512 + off;
            const char* src = smem + row * 512 + off;
#pragma unroll
            for (int j = 0; j < 4; j++) {
                u32x4 v = *(const u32x4*)(src + j * 16);
                *(u32x4*)(dst + j * 16) = v;
            }
        }
    }
}

// ---------------- mean pool per graph (batch sorted) ----------------
__global__ void k_pool(const unsigned short* __restrict__ hbf, const int* __restrict__ batch,
                       float* __restrict__ pooled) {
    __shared__ float part[4 * 512];
    __shared__ int se[2];
    int g = blockIdx.x, t = threadIdx.x, w = t >> 6, lane = t & 63;
    if (t == 0) {
        int lo = 0, hi = N_NODES;
        while (lo < hi) { int m = (lo + hi) >> 1; if (batch[m] < g) lo = m + 1; else hi = m; }
        se[0] = lo;
        int lo2 = lo; hi = N_NODES;
        while (lo2 < hi) { int m = (lo2 + hi) >> 1; if (batch[m] < g + 1) lo2 = m + 1; else hi = m; }
        se[1] = lo2;
    }
    __syncthreads();
    int s = se[0], e = se[1];
    float acc[8] = {0, 0, 0, 0, 0, 0, 0, 0};
    for (int row = s + w; row < e; row += 4) {
        u32x4 v = *(const u32x4*)&hbf[(size_t)row * 512 + lane * 8];
#pragma unroll
        for (int j = 0; j < 4; j++) {
            unsigned int uu = v[j];
            acc[2 * j]     += __uint_as_float(uu << 16);
            acc[2 * j + 1] += __uint_as_float(uu & 0xffff0000u);
        }
    }
#pragma unroll
    for (int j = 0; j < 8; j++) part[w * 512 + j * 64 + lane] = acc[j];
    __syncthreads();
    float cnt = fmaxf((float)(e - s), 1.f);
    for (int sidx = t; sidx < 512; sidx += 256) {
        float v = part[sidx] + part[512 + sidx] + part[1024 + sidx] + part[1536 + sidx];
        int col = (sidx & 63) * 8 + (sidx >> 6);
        pooled[(size_t)g * 512 + col] = v / cnt;
    }
}

// ---------------- final: out = pooled @ W_out + b_out (fp32), 8 graphs/block ----------------
__global__ __launch_bounds__(256)
void k_out(const float* __restrict__ pooled, const float* __restrict__ Wout,
           const float* __restrict__ bout, float* __restrict__ out) {
    __shared__ float pl[8 * 512];
    int t = threadIdx.x;
    int g0 = blockIdx.x * 8;
#pragma unroll
    for (int i = 0; i < 16; i++) {
        int idx = i * 256 + t;
        pl[idx] = pooled[(size_t)g0 * 512 + idx];
    }
    __syncthreads();
    int c0 = t * 2;
    float a[8][2];
#pragma unroll
    for (int g = 0; g < 8; g++) { a[g][0] = bout[c0]; a[g][1] = bout[c0 + 1]; }
    for (int k = 0; k < 512; k++) {
        float2 wv = *(const float2*)&Wout[(size_t)k * 512 + c0];
#pragma unroll
        for (int g = 0; g < 8; g++) {
            float p = pl[g * 512 + k];
            a[g][0] += p * wv.x;
            a[g][1] += p * wv.y;
        }
    }
#pragma unroll
    for (int g = 0; g < 8; g++) {
        out[(size_t)(g0 + g) * 512 + c0]     = a[g][0];
        out[(size_t)(g0 + g) * 512 + c0 + 1] = a[g][1];
    }
}

// ---------------- pack B: W_root -> fp8 frag order, W_neigh -> f16 frag order --------------
__global__ void k_pack_b(const float* __restrict__ Wr, const float* __restrict__ Wn,
                         unsigned char* __restrict__ Bp8, unsigned short* __restrict__ Bpf) {
    int tid = blockIdx.x * 256 + threadIdx.x;
    const int HALF = 3 * 16 * 32 * 64;
    if (tid >= 2 * HALF) return;
    bool isRoot = (tid < HALF);
    int t = isRoot ? tid : tid - HALF;
    int lane = t & 63;
    int u = t >> 6;
    int cf = u & 31; u >>= 5;
    int kt = u & 15;
    int l  = u >> 4;
    int col = cf * 16 + (lane & 15);
    int kr0 = kt * 32 + (lane >> 4) * 8;
    if (isRoot) {
        const float* W = Wr + (size_t)l * H * H;
        float v[8];
#pragma unroll
        for (int j = 0; j < 8; j++) v[j] = W[(size_t)(kr0 + j) * H + col];
        int w0 = __builtin_amdgcn_cvt_pk_fp8_f32(v[0], v[1], 0, false);
        w0 = __builtin_amdgcn_cvt_pk_fp8_f32(v[2], v[3], w0, true);
        int w1 = __builtin_amdgcn_cvt_pk_fp8_f32(v[4], v[5], 0, false);
        w1 = __builtin_amdgcn_cvt_pk_fp8_f32(v[6], v[7], w1, true);
        u32x2 o; o[0] = (unsigned int)w0; o[1] = (unsigned int)w1;
        *(u32x2*)&Bp8[(size_t)((l * 16 + kt) * 32 + cf) * 512 + lane * 8] = o;
    } else {
        const float* W = Wn + (size_t)l * H * H;
        unsigned int words[4];
#pragma unroll
        for (int p = 0; p < 4; p++) {
            float v0 = W[(size_t)(kr0 + 2 * p) * H + col];
            float v1 = W[(size_t)(kr0 + 2 * p + 1) * H + col];
            words[p] = ((unsigned int)f2h(v1) << 16) | (unsigned int)f2h(v0);
        }
        u32x4 v; v[0] = words[0]; v[1] = words[1]; v[2] = words[2]; v[3] = words[3];
        *(u32x4*)&Bpf[(size_t)((l * 16 + kt) * 32 + cf) * 512 + lane * 8] = v;
    }
}

extern "C" void kernel_launch(void* const* d_in, const int* in_sizes, int n_in,
                              void* d_out, int out_size, void* d_ws, size_t ws_size,
                              hipStream_t stream) {
    const float* x     = (const float*)d_in[0];
    const int*   ei    = (const int*)d_in[1];
    const int*   batch = (const int*)d_in[2];
    const float* Win   = (const float*)d_in[3];
    const float* bin   = (const float*)d_in[4];
    const float* Wr    = (const float*)d_in[5];
    const float* Wn    = (const float*)d_in[6];
    const float* bconv = (const float*)d_in[7];
    const float* gamma = (const float*)d_in[8];
    const float* beta  = (const float*)d_in[9];
    const float* Wout  = (const float*)d_in[10];
    const float* bout  = (const float*)d_in[11];
    float* out = (float*)d_out;

    char* p = (char*)d_ws;
    auto carve = [&](size_t bytes) { char* r = p; p += (bytes + 255) & ~(size_t)255; return r; };
    unsigned char*  h8a  = (unsigned char*)carve((size_t)N_NODES * 512);
    unsigned char*  h8b  = (unsigned char*)carve((size_t)N_NODES * 512);
    unsigned short* agg  = (unsigned short*)carve((size_t)N_NODES * 512 * 2);
    unsigned short* hout = (unsigned short*)carve((size_t)N_NODES * 512 * 2);
    unsigned char*  Bp8  = (unsigned char*)carve((size_t)3 * 16 * 32 * 64 * 8);
    unsigned short* Bpf  = (unsigned short*)carve((size_t)3 * 16 * 32 * 64 * 8 * 2);
    int* csr  = (int*)carve((size_t)N_EDGES * 4);
    int* deg  = (int*)carve((size_t)N_NODES * 4);
    int* off  = (int*)carve((size_t)(N_NODES + 1) * 4);
    int* cur  = (int*)carve((size_t)N_NODES * 4);
    int* bsum = (int*)carve(1024);
    float* pooled = (float*)carve((size_t)GRAPHS * H * 4);

    hipMemsetAsync(deg, 0, (size_t)N_NODES * 4, stream);
    k_count<<<(N_EDGES + 255) / 256, 256, 0, stream>>>(ei, deg);
    k_scan1<<<98, 512, 0, stream>>>(deg, off, bsum);
    k_scan2<<<1, 128, 0, stream>>>(bsum);
    k_scan3<<<(N_NODES + 255) / 256, 256, 0, stream>>>(off, bsum, cur);
    k_fill<<<(N_EDGES + 255) / 256, 256, 0, stream>>>(ei, cur, csr);
    k_gemm_in<<<(N_NODES + 15) / 16, 256, 0, stream>>>(x, Win, bin, h8a);
    k_pack_b<<<(2 * 3 * 16 * 32 * 64 + 255) / 256, 256, 0, stream>>>(Wr, Wn, Bp8, Bpf);

    unsigned char* hcur = h8a;
    unsigned char* hnxt = h8b;
    for (int l = 0; l < 3; l++) {
        k_aggregate<<<(N_NODES + 3) / 4, 256, 0, stream>>>(off, csr, hcur, agg);
        k_gemm_layer<<<(N_NODES + 63) / 64, 512, 65536, stream>>>(
            hcur, agg, hnxt, hout,
            Bp8 + (size_t)l * 16 * 16384, Bpf + (size_t)l * 16 * 16384,
            bconv + (size_t)l * H, gamma + (size_t)l * H, beta + (size_t)l * H,
            (l == 2) ? 1 : 0);
        unsigned char* tmp = hcur; hcur = hnxt; hnxt = tmp;
    }
    k_pool<<<GRAPHS, 256, 0, stream>>>(hout, batch, pooled);
    k_out<<<32, 256, 0, stream>>>(pooled, Wout, bout, out);
}